// Round 3
// baseline (1159.634 us; speedup 1.0000x reference)
//
#include <hip/hip_runtime.h>
#include <hip/hip_bf16.h>

// NonLocalBlock2D: x[8,256,64,64] fp32
// Pipeline:
//   k_split_x : transpose+split x -> xT_hi/xT_lo [b][n][c] bf16 (split ONCE)
//   k_split_w : stack+split weights [g;theta;phi] -> w_hi/w_lo [384][256]
//   k_proj    : pure 3-pass split-bf16 GEMM -> theta/phi [n][c] hi/lo, gT [c][n]
//   k_gemm1   : f fp32 = theta·phi (3-pass split-bf16); epilogue atomicMax cmax
//   k_exp     : E[n][m] = bf16(exp(f-cmax[m])), psum[16][m] partial column sums
//   k_prep    : crcp=1/sum(psum); gs[c][m] = bf16(g[c][m]*crcp[m])
//   k_gemm2   : pure bf16 GEMM partial[kc][n][c] = E·gs over m-chunk
//   k_reduce  : yT[b][n][c] bf16 = sum_kc partial
//   k_conv    : out = W·yT + Wb + x

#define IC   128
#define CIN  256
#define NPOS 4096
#define NB   8

typedef __attribute__((ext_vector_type(8))) short bf16x8;
typedef __attribute__((ext_vector_type(4))) float f32x4;
typedef __attribute__((ext_vector_type(4))) float fvec4;

#define MFMA(a, b, c) __builtin_amdgcn_mfma_f32_16x16x32_bf16((a), (b), (c), 0, 0, 0)

static __device__ inline unsigned short f2bf(float f) {
    unsigned int u = __builtin_bit_cast(unsigned int, f);
    u += 0x7fffu + ((u >> 16) & 1u);   // RNE
    return (unsigned short)(u >> 16);
}
static __device__ inline float bf2f(unsigned short u) {
    unsigned int v = ((unsigned int)u) << 16;
    return __builtin_bit_cast(float, v);
}
static __device__ inline void splitbf(float v, unsigned short& hi, unsigned short& lo) {
    hi = f2bf(v);
    lo = f2bf(v - bf2f(hi));
}
// Deterministic float atomic max (max is exact & order-independent).
static __device__ inline void atomicMaxFloat(float* addr, float val) {
    if (val >= 0.0f)
        atomicMax((int*)addr, __float_as_int(val));
    else
        atomicMin((unsigned int*)addr, (unsigned int)__float_as_int(val));
}

// ---------------- transpose + split x: [b][c][n] fp32 -> [b][n][c] bf16 hi/lo ----------------
__global__ __launch_bounds__(256) void k_split_x(
    const float* __restrict__ x, unsigned short* __restrict__ xh, unsigned short* __restrict__ xl)
{
    __shared__ float tile[64][65];
    const int b  = blockIdx.z;
    const int c0 = blockIdx.y * 64;
    const int n0 = blockIdx.x * 64;
    const int t  = threadIdx.x;
    {
        const int cc = t >> 4, nn = (t & 15) * 4;
        const float* src = x + ((size_t)b * CIN + c0) * NPOS + n0;
#pragma unroll
        for (int p = 0; p < 4; ++p) {
            fvec4 v = *reinterpret_cast<const fvec4*>(src + (size_t)(cc + p * 16) * NPOS + nn);
            tile[cc + p * 16][nn + 0] = v[0];
            tile[cc + p * 16][nn + 1] = v[1];
            tile[cc + p * 16][nn + 2] = v[2];
            tile[cc + p * 16][nn + 3] = v[3];
        }
    }
    __syncthreads();
    {
        const int c4 = (t & 15) * 4, nr = t >> 4;
#pragma unroll
        for (int p = 0; p < 4; ++p) {
            const int n = nr + p * 16;
            ushort4 h, l;
            splitbf(tile[c4 + 0][n], h.x, l.x);
            splitbf(tile[c4 + 1][n], h.y, l.y);
            splitbf(tile[c4 + 2][n], h.z, l.z);
            splitbf(tile[c4 + 3][n], h.w, l.w);
            size_t off = ((size_t)b * NPOS + n0 + n) * CIN + c0 + c4;
            *reinterpret_cast<ushort4*>(xh + off) = h;
            *reinterpret_cast<ushort4*>(xl + off) = l;
        }
    }
}

// ---------------- split weights, stacked [g(0:128); theta(128:256); phi(256:384)] ----------------
__global__ __launch_bounds__(256) void k_split_w(
    const float* __restrict__ gw, const float* __restrict__ tw, const float* __restrict__ pw,
    unsigned short* __restrict__ wh, unsigned short* __restrict__ wl)
{
    const int idx = (blockIdx.x * 256 + threadIdx.x) * 4;   // over 384*256
    const int row = idx >> 8, col = idx & 255;
    const float* src = (row < 128) ? (gw + row * 256)
                     : (row < 256) ? (tw + (row - 128) * 256)
                                   : (pw + (row - 256) * 256);
    fvec4 v = *reinterpret_cast<const fvec4*>(src + col);
    ushort4 h, l;
    splitbf(v[0], h.x, l.x);
    splitbf(v[1], h.y, l.y);
    splitbf(v[2], h.z, l.z);
    splitbf(v[3], h.w, l.w);
    *reinterpret_cast<ushort4*>(wh + idx) = h;
    *reinterpret_cast<ushort4*>(wl + idx) = l;
}

// ---------------- projections: pure 3-pass split-bf16 GEMM ----------------
__global__ __launch_bounds__(256) void k_proj(
    const unsigned short* __restrict__ xh, const unsigned short* __restrict__ xl,
    const unsigned short* __restrict__ wh, const unsigned short* __restrict__ wl,
    const float* __restrict__ gb, const float* __restrict__ tb, const float* __restrict__ pb,
    unsigned short* __restrict__ th_hi, unsigned short* __restrict__ th_lo,
    unsigned short* __restrict__ ph_hi, unsigned short* __restrict__ ph_lo,
    unsigned short* __restrict__ gT)
{
    const int w    = threadIdx.x >> 6;
    const int lane = threadIdx.x & 63;
    const int lrow = lane & 15;
    const int kg   = lane >> 4;
    const int b    = blockIdx.z;
    const int c0   = blockIdx.y * 64 + w * 16;   // [0,384)
    const int n0   = blockIdx.x * 64;

    const unsigned short* Xh = xh + (size_t)b * NPOS * CIN;
    const unsigned short* Xl = xl + (size_t)b * NPOS * CIN;

    f32x4 acc[4] = {};
#pragma unroll
    for (int ks = 0; ks < 8; ++ks) {
        const int k = ks * 32 + kg * 8;
        bf16x8 ah = *reinterpret_cast<const bf16x8*>(wh + (size_t)(c0 + lrow) * CIN + k);
        bf16x8 al = *reinterpret_cast<const bf16x8*>(wl + (size_t)(c0 + lrow) * CIN + k);
#pragma unroll
        for (int i = 0; i < 4; ++i) {
            bf16x8 bh = *reinterpret_cast<const bf16x8*>(Xh + (size_t)(n0 + i * 16 + lrow) * CIN + k);
            bf16x8 bl = *reinterpret_cast<const bf16x8*>(Xl + (size_t)(n0 + i * 16 + lrow) * CIN + k);
            acc[i] = MFMA(ah, bh, acc[i]);
            acc[i] = MFMA(ah, bl, acc[i]);
            acc[i] = MFMA(al, bh, acc[i]);
        }
    }
    const int set = c0 >> 7;                 // 0:g 1:theta 2:phi
    const int cb  = (c0 - set * 128) + kg * 4;
    if (set == 0) {
#pragma unroll
        for (int i = 0; i < 4; ++i) {
            const int n = n0 + i * 16 + lrow;
#pragma unroll
            for (int r = 0; r < 4; ++r)
                gT[((size_t)b * IC + cb + r) * NPOS + n] = f2bf(acc[i][r] + gb[cb + r]);
        }
    } else {
        const float* Bi = (set == 1) ? tb : pb;
        unsigned short* hi = (set == 1) ? th_hi : ph_hi;
        unsigned short* lo = (set == 1) ? th_lo : ph_lo;
#pragma unroll
        for (int i = 0; i < 4; ++i) {
            const int n = n0 + i * 16 + lrow;
            ushort4 vh, vl;
            splitbf(acc[i][0] + Bi[cb + 0], vh.x, vl.x);
            splitbf(acc[i][1] + Bi[cb + 1], vh.y, vl.y);
            splitbf(acc[i][2] + Bi[cb + 2], vh.z, vl.z);
            splitbf(acc[i][3] + Bi[cb + 3], vh.w, vl.w);
            size_t off = ((size_t)b * NPOS + n) * IC + cb;
            *reinterpret_cast<ushort4*>(hi + off) = vh;
            *reinterpret_cast<ushort4*>(lo + off) = vl;
        }
    }
}

// ---------------- init cmax for all batches ----------------
__global__ __launch_bounds__(256) void k_init_cmax(float* __restrict__ cmax)
{
    cmax[blockIdx.x * 256 + threadIdx.x] = -3.0e38f;
}

// ---- GEMM1: f[n][m] = theta[n]·phi[m]; epilogue folds column max into cmax ----
__global__ __launch_bounds__(256) void k_gemm1(
    const unsigned short* __restrict__ th_hi, const unsigned short* __restrict__ th_lo,
    const unsigned short* __restrict__ ph_hi, const unsigned short* __restrict__ ph_lo,
    float* __restrict__ f, float* __restrict__ cmax, int b)
{
    const int w    = threadIdx.x >> 6;
    const int lane = threadIdx.x & 63;
    const int lrow = lane & 15;
    const int kg   = lane >> 4;
    const int tid  = blockIdx.x * 4 + w;      // 0..4095
    const int n0   = (tid >> 6) * 64;
    const int m0   = (tid & 63) * 64;

    const unsigned short* Ah = th_hi + (size_t)b * NPOS * IC;
    const unsigned short* Al = th_lo + (size_t)b * NPOS * IC;
    const unsigned short* Bh = ph_hi + (size_t)b * NPOS * IC;
    const unsigned short* Bl = ph_lo + (size_t)b * NPOS * IC;

    f32x4 acc[4][4] = {};
#pragma unroll
    for (int ks = 0; ks < 4; ++ks) {
        const int k = ks * 32 + kg * 8;
        bf16x8 ah[4], al[4], bh[4], bl[4];
#pragma unroll
        for (int i = 0; i < 4; ++i) {
            ah[i] = *reinterpret_cast<const bf16x8*>(Ah + (size_t)(n0 + i * 16 + lrow) * IC + k);
            al[i] = *reinterpret_cast<const bf16x8*>(Al + (size_t)(n0 + i * 16 + lrow) * IC + k);
            bh[i] = *reinterpret_cast<const bf16x8*>(Bh + (size_t)(m0 + i * 16 + lrow) * IC + k);
            bl[i] = *reinterpret_cast<const bf16x8*>(Bl + (size_t)(m0 + i * 16 + lrow) * IC + k);
        }
#pragma unroll
        for (int i = 0; i < 4; ++i)
#pragma unroll
            for (int j = 0; j < 4; ++j) {
                acc[i][j] = MFMA(ah[i], bh[j], acc[i][j]);
                acc[i][j] = MFMA(ah[i], bl[j], acc[i][j]);
                acc[i][j] = MFMA(al[i], bh[j], acc[i][j]);
            }
    }
#pragma unroll
    for (int i = 0; i < 4; ++i)
#pragma unroll
        for (int j = 0; j < 4; ++j)
#pragma unroll
            for (int r = 0; r < 4; ++r)
                f[(size_t)(n0 + i * 16 + kg * 4 + r) * NPOS + m0 + j * 16 + lrow] = acc[i][j][r];

    // column max over this wave's 64 rows, for its 64 columns
#pragma unroll
    for (int j = 0; j < 4; ++j) {
        float cm = -3.0e38f;
#pragma unroll
        for (int i = 0; i < 4; ++i)
#pragma unroll
            for (int r = 0; r < 4; ++r)
                cm = fmaxf(cm, acc[i][j][r]);
        cm = fmaxf(cm, __shfl_xor(cm, 16));
        cm = fmaxf(cm, __shfl_xor(cm, 32));
        if (kg == 0)
            atomicMaxFloat(&cmax[m0 + j * 16 + lrow], cm);
    }
}

// ---------------- E = bf16(exp(f - cmax)), psum partial column sums ----------------
__global__ __launch_bounds__(256) void k_exp(
    const float* __restrict__ f, const float* __restrict__ cmax,
    unsigned short* __restrict__ E, float* __restrict__ psum)
{
    const int t    = threadIdx.x;
    const int c4   = (t & 63) * 4;
    const int rsub = t >> 6;
    const int col  = blockIdx.x * 256 + c4;
    fvec4 cm = *reinterpret_cast<const fvec4*>(cmax + col);
    fvec4 s = {0.f, 0.f, 0.f, 0.f};
    const int r0 = blockIdx.y * 256 + rsub;
#pragma unroll 4
    for (int it = 0; it < 64; ++it) {
        const int row = r0 + it * 4;
        fvec4 v = *reinterpret_cast<const fvec4*>(f + (size_t)row * NPOS + col);
        float e0 = __expf(v[0] - cm[0]);
        float e1 = __expf(v[1] - cm[1]);
        float e2 = __expf(v[2] - cm[2]);
        float e3 = __expf(v[3] - cm[3]);
        s[0] += e0; s[1] += e1; s[2] += e2; s[3] += e3;
        ushort4 o;
        o.x = f2bf(e0); o.y = f2bf(e1); o.z = f2bf(e2); o.w = f2bf(e3);
        *reinterpret_cast<ushort4*>(E + (size_t)row * NPOS + col) = o;
    }
    __shared__ fvec4 sm[256];
    sm[t] = s;
    __syncthreads();
    if (rsub == 0) {
        fvec4 a = sm[t], b = sm[t + 64], c = sm[t + 128], d = sm[t + 192];
        fvec4 o;
        o[0] = (a[0] + b[0]) + (c[0] + d[0]);
        o[1] = (a[1] + b[1]) + (c[1] + d[1]);
        o[2] = (a[2] + b[2]) + (c[2] + d[2]);
        o[3] = (a[3] + b[3]) + (c[3] + d[3]);
        *reinterpret_cast<fvec4*>(psum + (size_t)blockIdx.y * NPOS + col) = o;
    }
}

// ---------------- crcp + scale g: gs[c][m] = bf16(g[c][m] / colsum[m]) ----------------
__global__ __launch_bounds__(256) void k_prep(
    const float* __restrict__ psum, const unsigned short* __restrict__ gTb,
    unsigned short* __restrict__ gs)
{
    const int m = blockIdx.x * 256 + threadIdx.x;
    float s = 0.f;
#pragma unroll
    for (int i = 0; i < 16; ++i)
        s += psum[(size_t)i * NPOS + m];
    const float rc = 1.0f / s;
    const int cb = blockIdx.y * 16;
#pragma unroll
    for (int j = 0; j < 16; ++j) {
        const int c = cb + j;
        gs[(size_t)c * NPOS + m] = f2bf(bf2f(gTb[(size_t)c * NPOS + m]) * rc);
    }
}

// ---------------- GEMM2: partial[kc][n][c] = sum_{m chunk} gs[c][m]·E[n][m] ----------------
__global__ __launch_bounds__(256) void k_gemm2(
    const unsigned short* __restrict__ E, const unsigned short* __restrict__ gs,
    float* __restrict__ partial)
{
    const int w    = threadIdx.x >> 6;
    const int lane = threadIdx.x & 63;
    const int lrow = lane & 15;
    const int kg   = lane >> 4;
    const int gwid = blockIdx.x * 4 + w;      // 0..1023
    const int kc   = gwid & 3;
    const int n0   = (gwid >> 2) * 16;

    f32x4 acc[8] = {};
    const unsigned short* Erow = E + (size_t)(n0 + lrow) * NPOS + kc * 1024;
#pragma unroll 4
    for (int ks = 0; ks < 32; ++ks) {
        const int k = ks * 32 + kg * 8;
        bf16x8 bv = *reinterpret_cast<const bf16x8*>(Erow + k);
#pragma unroll
        for (int ci = 0; ci < 8; ++ci) {
            bf16x8 av = *reinterpret_cast<const bf16x8*>(gs + (size_t)(ci * 16 + lrow) * NPOS + kc * 1024 + k);
            acc[ci] = MFMA(av, bv, acc[ci]);
        }
    }
#pragma unroll
    for (int ci = 0; ci < 8; ++ci)
        *reinterpret_cast<fvec4*>(partial + ((size_t)kc * NPOS + n0 + lrow) * IC + ci * 16 + kg * 4) = acc[ci];
}

// ---------------- reduce partials -> yT[b][n][c] bf16 ----------------
__global__ __launch_bounds__(256) void k_reduce(
    const float* __restrict__ partial, unsigned short* __restrict__ yT, int b)
{
    const int idx = blockIdx.x * 256 + threadIdx.x;   // over NPOS*IC/4
    const fvec4* p = reinterpret_cast<const fvec4*>(partial);
    fvec4 s = p[idx];
#pragma unroll
    for (int kc = 1; kc < 4; ++kc) {
        fvec4 v = p[(size_t)kc * (NPOS * IC / 4) + idx];
        s[0] += v[0]; s[1] += v[1]; s[2] += v[2]; s[3] += v[3];
    }
    ushort4 o;
    o.x = f2bf(s[0]); o.y = f2bf(s[1]); o.z = f2bf(s[2]); o.w = f2bf(s[3]);
    *reinterpret_cast<ushort4*>(yT + (size_t)b * NPOS * IC + (size_t)idx * 4) = o;
}

// ---------------- final conv + residual: out[b][o][n] = x + Wb[o] + sum_ic W[o][ic] y[n][ic] ----------------
__global__ __launch_bounds__(256) void k_conv(
    const float* __restrict__ x, const float* __restrict__ Ww, const float* __restrict__ Wb,
    const unsigned short* __restrict__ yT, float* __restrict__ out)
{
    const int w    = threadIdx.x >> 6;
    const int lane = threadIdx.x & 63;
    const int lrow = lane & 15;
    const int kg   = lane >> 4;
    const int b  = blockIdx.z;
    const int o0 = blockIdx.y * 16;
    const int n0 = (blockIdx.x * 4 + w) * 16;

    const unsigned short* Y = yT + (size_t)b * NPOS * IC;
    f32x4 acc = {0.f, 0.f, 0.f, 0.f};
#pragma unroll
    for (int ks = 0; ks < 4; ++ks) {
        const int k = ks * 32 + kg * 8;
        const float* wr = Ww + (o0 + lrow) * IC + k;
        bf16x8 av, bv;
#pragma unroll
        for (int j = 0; j < 8; ++j)
            av[j] = (short)f2bf(wr[j]);
        bv = *reinterpret_cast<const bf16x8*>(Y + (size_t)(n0 + lrow) * IC + k);
        acc = MFMA(av, bv, acc);
    }
    const int n = n0 + lrow;
#pragma unroll
    for (int r = 0; r < 4; ++r) {
        const int o = o0 + kg * 4 + r;
        const size_t off = ((size_t)b * CIN + o) * NPOS + n;
        out[off] = acc[r] + x[off] + Wb[o];
    }
}

extern "C" void kernel_launch(void* const* d_in, const int* in_sizes, int n_in,
                              void* d_out, int out_size, void* d_ws, size_t ws_size,
                              hipStream_t stream)
{
    const float* x  = (const float*)d_in[0];
    const float* gw = (const float*)d_in[1];
    const float* gb = (const float*)d_in[2];
    const float* tw = (const float*)d_in[3];
    const float* tb = (const float*)d_in[4];
    const float* pw = (const float*)d_in[5];
    const float* pb = (const float*)d_in[6];
    const float* Ww = (const float*)d_in[7];
    const float* Wb = (const float*)d_in[8];
    float* out = (float*)d_out;

    char* ws = (char*)d_ws;
    size_t off = 0;
    auto alloc = [&](size_t bytes) -> char* {
        char* p = ws + off;
        off += (bytes + 255) & ~(size_t)255;
        return p;
    };
    const size_t xTB   = (size_t)NB * NPOS * CIN * 2;          // 16.8 MB each
    const size_t projB = (size_t)NB * NPOS * IC * 2;           // 8 MB each
    unsigned short* xT_h = (unsigned short*)alloc(xTB);
    unsigned short* xT_l = (unsigned short*)alloc(xTB);        // xT region doubles as E later
    unsigned short* w_h  = (unsigned short*)alloc((size_t)384 * 256 * 2);
    unsigned short* w_l  = (unsigned short*)alloc((size_t)384 * 256 * 2);
    unsigned short* th_hi = (unsigned short*)alloc(projB);
    unsigned short* th_lo = (unsigned short*)alloc(projB);
    unsigned short* ph_hi = (unsigned short*)alloc(projB);
    unsigned short* ph_lo = (unsigned short*)alloc(projB);
    unsigned short* gT    = (unsigned short*)alloc(projB);
    float* f       = (float*)alloc((size_t)NPOS * NPOS * 4);   // 64 MB (per-batch reuse)
    float* cmax    = (float*)alloc((size_t)NB * NPOS * 4);
    float* psum    = (float*)alloc((size_t)16 * NPOS * 4);
    unsigned short* gs = (unsigned short*)alloc((size_t)IC * NPOS * 2);
    float* partial = (float*)alloc((size_t)4 * NPOS * IC * 4); // 8 MB (per-batch reuse)
    unsigned short* yT = (unsigned short*)alloc(projB);        // 8 MB
    unsigned short* E  = xT_h;   // alias: xT dead after k_proj; E = 32 MB <= 33.6 MB

    k_split_x<<<dim3(64, 4, 8), 256, 0, stream>>>(x, xT_h, xT_l);
    k_split_w<<<96, 256, 0, stream>>>(gw, tw, pw, w_h, w_l);
    k_init_cmax<<<NB * NPOS / 256, 256, 0, stream>>>(cmax);
    k_proj<<<dim3(64, 6, 8), 256, 0, stream>>>(xT_h, xT_l, w_h, w_l, gb, tb, pb,
                                               th_hi, th_lo, ph_hi, ph_lo, gT);

    for (int b = 0; b < NB; ++b) {
        float* cm = cmax + (size_t)b * NPOS;
        k_gemm1<<<1024, 256, 0, stream>>>(th_hi, th_lo, ph_hi, ph_lo, f, cm, b);
        k_exp<<<dim3(16, 16), 256, 0, stream>>>(f, cm, E, psum);
        k_prep<<<dim3(16, 8), 256, 0, stream>>>(psum, gT + (size_t)b * IC * NPOS, gs);
        k_gemm2<<<256, 256, 0, stream>>>(E, gs, partial);
        k_reduce<<<512, 256, 0, stream>>>(partial, yT, b);
    }
    k_conv<<<dim3(64, 16, 8), 256, 0, stream>>>(x, Ww, Wb, yT, out);
}

// Round 4
// 841.813 us; speedup vs baseline: 1.3775x; 1.3775x over previous
//
#include <hip/hip_runtime.h>
#include <hip/hip_bf16.h>

// NonLocalBlock2D: x[8,256,64,64] fp32
// Pipeline:
//   k_split_x : transpose+split x -> xT_hi/xT_lo [b][n][c] bf16 (split ONCE)
//   k_split_w : stack+split weights [g;theta;phi] -> w_hi/w_lo [384][256]
//   k_cvt_w   : W -> bf16 [256][128]
//   k_proj    : 3-pass split-bf16 GEMM, 64x64/wave -> theta/phi [n][c] hi/lo, gT [c][n]
//   k_gemm1   : f fp32 = theta·phi (3-pass split-bf16); epilogue atomicMax cmax
//   k_exp     : E[n][m] = bf16(exp(f-cmax[m])), psum[64][m] partial column sums
//   k_prep    : crcp=1/sum(psum); gs[c][m] = bf16(g[c][m]*crcp[m])
//   k_gemm2   : pure bf16 GEMM partial[kc][n][c] = E·gs over m-chunk (kc=8)
//   k_reduce  : yT[b][n][c] bf16 = sum_kc partial
//   k_conv    : out = W·yT + Wb + x  (64x64/wave)

#define IC   128
#define CIN  256
#define NPOS 4096
#define NB   8

typedef __attribute__((ext_vector_type(8))) short bf16x8;
typedef __attribute__((ext_vector_type(4))) float f32x4;
typedef __attribute__((ext_vector_type(4))) float fvec4;

#define MFMA(a, b, c) __builtin_amdgcn_mfma_f32_16x16x32_bf16((a), (b), (c), 0, 0, 0)

static __device__ inline unsigned short f2bf(float f) {
    unsigned int u = __builtin_bit_cast(unsigned int, f);
    u += 0x7fffu + ((u >> 16) & 1u);   // RNE
    return (unsigned short)(u >> 16);
}
static __device__ inline float bf2f(unsigned short u) {
    unsigned int v = ((unsigned int)u) << 16;
    return __builtin_bit_cast(float, v);
}
static __device__ inline void splitbf(float v, unsigned short& hi, unsigned short& lo) {
    hi = f2bf(v);
    lo = f2bf(v - bf2f(hi));
}
// Deterministic float atomic max (max is exact & order-independent).
static __device__ inline void atomicMaxFloat(float* addr, float val) {
    if (val >= 0.0f)
        atomicMax((int*)addr, __float_as_int(val));
    else
        atomicMin((unsigned int*)addr, (unsigned int)__float_as_int(val));
}

// ---------------- transpose + split x: [b][c][n] fp32 -> [b][n][c] bf16 hi/lo ----------------
__global__ __launch_bounds__(256) void k_split_x(
    const float* __restrict__ x, unsigned short* __restrict__ xh, unsigned short* __restrict__ xl)
{
    __shared__ float tile[64][65];
    const int b  = blockIdx.z;
    const int c0 = blockIdx.y * 64;
    const int n0 = blockIdx.x * 64;
    const int t  = threadIdx.x;
    {
        const int cc = t >> 4, nn = (t & 15) * 4;
        const float* src = x + ((size_t)b * CIN + c0) * NPOS + n0;
#pragma unroll
        for (int p = 0; p < 4; ++p) {
            fvec4 v = *reinterpret_cast<const fvec4*>(src + (size_t)(cc + p * 16) * NPOS + nn);
            tile[cc + p * 16][nn + 0] = v[0];
            tile[cc + p * 16][nn + 1] = v[1];
            tile[cc + p * 16][nn + 2] = v[2];
            tile[cc + p * 16][nn + 3] = v[3];
        }
    }
    __syncthreads();
    {
        const int c4 = (t & 15) * 4, nr = t >> 4;
#pragma unroll
        for (int p = 0; p < 4; ++p) {
            const int n = nr + p * 16;
            ushort4 h, l;
            splitbf(tile[c4 + 0][n], h.x, l.x);
            splitbf(tile[c4 + 1][n], h.y, l.y);
            splitbf(tile[c4 + 2][n], h.z, l.z);
            splitbf(tile[c4 + 3][n], h.w, l.w);
            size_t off = ((size_t)b * NPOS + n0 + n) * CIN + c0 + c4;
            *reinterpret_cast<ushort4*>(xh + off) = h;
            *reinterpret_cast<ushort4*>(xl + off) = l;
        }
    }
}

// ---------------- split weights, stacked [g(0:128); theta(128:256); phi(256:384)] ----------------
__global__ __launch_bounds__(256) void k_split_w(
    const float* __restrict__ gw, const float* __restrict__ tw, const float* __restrict__ pw,
    unsigned short* __restrict__ wh, unsigned short* __restrict__ wl)
{
    const int idx = (blockIdx.x * 256 + threadIdx.x) * 4;   // over 384*256
    const int row = idx >> 8, col = idx & 255;
    const float* src = (row < 128) ? (gw + row * 256)
                     : (row < 256) ? (tw + (row - 128) * 256)
                                   : (pw + (row - 256) * 256);
    fvec4 v = *reinterpret_cast<const fvec4*>(src + col);
    ushort4 h, l;
    splitbf(v[0], h.x, l.x);
    splitbf(v[1], h.y, l.y);
    splitbf(v[2], h.z, l.z);
    splitbf(v[3], h.w, l.w);
    *reinterpret_cast<ushort4*>(wh + idx) = h;
    *reinterpret_cast<ushort4*>(wl + idx) = l;
}

// ---------------- convert final W to bf16 [256][128] ----------------
__global__ __launch_bounds__(256) void k_cvt_w(
    const float* __restrict__ Ww, unsigned short* __restrict__ Wbf)
{
    const int idx = (blockIdx.x * 256 + threadIdx.x) * 4;   // over 256*128
    fvec4 v = *reinterpret_cast<const fvec4*>(Ww + idx);
    ushort4 o;
    o.x = f2bf(v[0]); o.y = f2bf(v[1]); o.z = f2bf(v[2]); o.w = f2bf(v[3]);
    *reinterpret_cast<ushort4*>(Wbf + idx) = o;
}

// ---------------- projections: 3-pass split-bf16 GEMM, 64x64 per wave ----------------
__global__ __launch_bounds__(256) void k_proj(
    const unsigned short* __restrict__ xh, const unsigned short* __restrict__ xl,
    const unsigned short* __restrict__ wh, const unsigned short* __restrict__ wl,
    const float* __restrict__ gb, const float* __restrict__ tb, const float* __restrict__ pb,
    unsigned short* __restrict__ th_hi, unsigned short* __restrict__ th_lo,
    unsigned short* __restrict__ ph_hi, unsigned short* __restrict__ ph_lo,
    unsigned short* __restrict__ gT)
{
    const int w    = threadIdx.x >> 6;
    const int lane = threadIdx.x & 63;
    const int lrow = lane & 15;
    const int kg   = lane >> 4;
    const int b    = blockIdx.z;
    const int c0   = blockIdx.y * 64;              // [0,384) in steps of 64
    const int n0   = blockIdx.x * 256 + w * 64;

    const unsigned short* Xh = xh + (size_t)b * NPOS * CIN;
    const unsigned short* Xl = xl + (size_t)b * NPOS * CIN;

    f32x4 acc[4][4] = {};
#pragma unroll
    for (int ks = 0; ks < 8; ++ks) {
        const int k = ks * 32 + kg * 8;
        bf16x8 ah[4], al[4], bh[4], bl[4];
#pragma unroll
        for (int i = 0; i < 4; ++i) {
            ah[i] = *reinterpret_cast<const bf16x8*>(wh + (size_t)(c0 + i * 16 + lrow) * CIN + k);
            al[i] = *reinterpret_cast<const bf16x8*>(wl + (size_t)(c0 + i * 16 + lrow) * CIN + k);
            bh[i] = *reinterpret_cast<const bf16x8*>(Xh + (size_t)(n0 + i * 16 + lrow) * CIN + k);
            bl[i] = *reinterpret_cast<const bf16x8*>(Xl + (size_t)(n0 + i * 16 + lrow) * CIN + k);
        }
#pragma unroll
        for (int i = 0; i < 4; ++i)
#pragma unroll
            for (int j = 0; j < 4; ++j) {
                acc[i][j] = MFMA(ah[i], bh[j], acc[i][j]);
                acc[i][j] = MFMA(ah[i], bl[j], acc[i][j]);
                acc[i][j] = MFMA(al[i], bh[j], acc[i][j]);
            }
    }
    const int set = c0 >> 7;                 // 0:g 1:theta 2:phi
    if (set == 0) {
#pragma unroll
        for (int i = 0; i < 4; ++i) {
            const int c = c0 + i * 16 + kg * 4;  // local since c0<128 for set 0
#pragma unroll
            for (int j = 0; j < 4; ++j) {
                const int n = n0 + j * 16 + lrow;
#pragma unroll
                for (int r = 0; r < 4; ++r)
                    gT[((size_t)b * IC + c + r) * NPOS + n] = f2bf(acc[i][j][r] + gb[c + r]);
            }
        }
    } else {
        const float* Bi = (set == 1) ? tb : pb;
        unsigned short* hi = (set == 1) ? th_hi : ph_hi;
        unsigned short* lo = (set == 1) ? th_lo : ph_lo;
        const int cl0 = (c0 & 127);
#pragma unroll
        for (int i = 0; i < 4; ++i) {
            const int c = cl0 + i * 16 + kg * 4;
#pragma unroll
            for (int j = 0; j < 4; ++j) {
                const int n = n0 + j * 16 + lrow;
                ushort4 vh, vl;
                splitbf(acc[i][j][0] + Bi[c + 0], vh.x, vl.x);
                splitbf(acc[i][j][1] + Bi[c + 1], vh.y, vl.y);
                splitbf(acc[i][j][2] + Bi[c + 2], vh.z, vl.z);
                splitbf(acc[i][j][3] + Bi[c + 3], vh.w, vl.w);
                size_t off = ((size_t)b * NPOS + n) * IC + c;
                *reinterpret_cast<ushort4*>(hi + off) = vh;
                *reinterpret_cast<ushort4*>(lo + off) = vl;
            }
        }
    }
}

// ---------------- init cmax for all batches ----------------
__global__ __launch_bounds__(256) void k_init_cmax(float* __restrict__ cmax)
{
    cmax[blockIdx.x * 256 + threadIdx.x] = -3.0e38f;
}

// ---- GEMM1: f[n][m] = theta[n]·phi[m]; epilogue folds column max into cmax ----
__global__ __launch_bounds__(256) void k_gemm1(
    const unsigned short* __restrict__ th_hi, const unsigned short* __restrict__ th_lo,
    const unsigned short* __restrict__ ph_hi, const unsigned short* __restrict__ ph_lo,
    float* __restrict__ f, float* __restrict__ cmax, int b)
{
    const int w    = threadIdx.x >> 6;
    const int lane = threadIdx.x & 63;
    const int lrow = lane & 15;
    const int kg   = lane >> 4;
    const int tid  = blockIdx.x * 4 + w;      // 0..4095
    const int n0   = (tid >> 6) * 64;
    const int m0   = (tid & 63) * 64;

    const unsigned short* Ah = th_hi + (size_t)b * NPOS * IC;
    const unsigned short* Al = th_lo + (size_t)b * NPOS * IC;
    const unsigned short* Bh = ph_hi + (size_t)b * NPOS * IC;
    const unsigned short* Bl = ph_lo + (size_t)b * NPOS * IC;

    f32x4 acc[4][4] = {};
#pragma unroll
    for (int ks = 0; ks < 4; ++ks) {
        const int k = ks * 32 + kg * 8;
        bf16x8 ah[4], al[4], bh[4], bl[4];
#pragma unroll
        for (int i = 0; i < 4; ++i) {
            ah[i] = *reinterpret_cast<const bf16x8*>(Ah + (size_t)(n0 + i * 16 + lrow) * IC + k);
            al[i] = *reinterpret_cast<const bf16x8*>(Al + (size_t)(n0 + i * 16 + lrow) * IC + k);
            bh[i] = *reinterpret_cast<const bf16x8*>(Bh + (size_t)(m0 + i * 16 + lrow) * IC + k);
            bl[i] = *reinterpret_cast<const bf16x8*>(Bl + (size_t)(m0 + i * 16 + lrow) * IC + k);
        }
#pragma unroll
        for (int i = 0; i < 4; ++i)
#pragma unroll
            for (int j = 0; j < 4; ++j) {
                acc[i][j] = MFMA(ah[i], bh[j], acc[i][j]);
                acc[i][j] = MFMA(ah[i], bl[j], acc[i][j]);
                acc[i][j] = MFMA(al[i], bh[j], acc[i][j]);
            }
    }
#pragma unroll
    for (int i = 0; i < 4; ++i)
#pragma unroll
        for (int j = 0; j < 4; ++j)
#pragma unroll
            for (int r = 0; r < 4; ++r)
                f[(size_t)(n0 + i * 16 + kg * 4 + r) * NPOS + m0 + j * 16 + lrow] = acc[i][j][r];

    // column max over this wave's 64 rows, for its 64 columns
#pragma unroll
    for (int j = 0; j < 4; ++j) {
        float cm = -3.0e38f;
#pragma unroll
        for (int i = 0; i < 4; ++i)
#pragma unroll
            for (int r = 0; r < 4; ++r)
                cm = fmaxf(cm, acc[i][j][r]);
        cm = fmaxf(cm, __shfl_xor(cm, 16));
        cm = fmaxf(cm, __shfl_xor(cm, 32));
        if (kg == 0)
            atomicMaxFloat(&cmax[m0 + j * 16 + lrow], cm);
    }
}

// ---------------- E = bf16(exp(f - cmax)), psum[64] partial column sums ----------------
__global__ __launch_bounds__(256) void k_exp(
    const float* __restrict__ f, const float* __restrict__ cmax,
    unsigned short* __restrict__ E, float* __restrict__ psum)
{
    const int t    = threadIdx.x;
    const int c4   = (t & 63) * 4;
    const int rsub = t >> 6;
    const int col  = blockIdx.x * 256 + c4;
    fvec4 cm = *reinterpret_cast<const fvec4*>(cmax + col);
    fvec4 s = {0.f, 0.f, 0.f, 0.f};
    const int r0 = blockIdx.y * 64 + rsub;
#pragma unroll 4
    for (int it = 0; it < 16; ++it) {
        const int row = r0 + it * 4;
        fvec4 v = *reinterpret_cast<const fvec4*>(f + (size_t)row * NPOS + col);
        float e0 = __expf(v[0] - cm[0]);
        float e1 = __expf(v[1] - cm[1]);
        float e2 = __expf(v[2] - cm[2]);
        float e3 = __expf(v[3] - cm[3]);
        s[0] += e0; s[1] += e1; s[2] += e2; s[3] += e3;
        ushort4 o;
        o.x = f2bf(e0); o.y = f2bf(e1); o.z = f2bf(e2); o.w = f2bf(e3);
        *reinterpret_cast<ushort4*>(E + (size_t)row * NPOS + col) = o;
    }
    __shared__ fvec4 sm[256];
    sm[t] = s;
    __syncthreads();
    if (rsub == 0) {
        fvec4 a = sm[t], b = sm[t + 64], c = sm[t + 128], d = sm[t + 192];
        fvec4 o;
        o[0] = (a[0] + b[0]) + (c[0] + d[0]);
        o[1] = (a[1] + b[1]) + (c[1] + d[1]);
        o[2] = (a[2] + b[2]) + (c[2] + d[2]);
        o[3] = (a[3] + b[3]) + (c[3] + d[3]);
        *reinterpret_cast<fvec4*>(psum + (size_t)blockIdx.y * NPOS + col) = o;
    }
}

// ---------------- crcp + scale g: gs[c][m] = bf16(g[c][m] / colsum[m]) ----------------
__global__ __launch_bounds__(256) void k_prep(
    const float* __restrict__ psum, const unsigned short* __restrict__ gTb,
    unsigned short* __restrict__ gs)
{
    const int m = blockIdx.x * 256 + threadIdx.x;
    float s = 0.f;
#pragma unroll 8
    for (int i = 0; i < 64; ++i)
        s += psum[(size_t)i * NPOS + m];
    const float rc = 1.0f / s;
    const int cb = blockIdx.y * 16;
#pragma unroll
    for (int j = 0; j < 16; ++j) {
        const int c = cb + j;
        gs[(size_t)c * NPOS + m] = f2bf(bf2f(gTb[(size_t)c * NPOS + m]) * rc);
    }
}

// ---------------- GEMM2: partial[kc][n][c] = sum_{m chunk} gs[c][m]·E[n][m] ----------------
__global__ __launch_bounds__(256) void k_gemm2(
    const unsigned short* __restrict__ E, const unsigned short* __restrict__ gs,
    float* __restrict__ partial)
{
    const int w    = threadIdx.x >> 6;
    const int lane = threadIdx.x & 63;
    const int lrow = lane & 15;
    const int kg   = lane >> 4;
    const int gwid = blockIdx.x * 4 + w;      // 0..2047
    const int kc   = gwid & 7;                // m-chunk of 512
    const int nb   = (gwid >> 3) & 127;       // n-block of 32
    const int cb   = gwid >> 10;              // c-block of 64
    const int c0   = cb * 64;
    const int n0   = nb * 32;

    f32x4 acc[4][2] = {};
#pragma unroll 4
    for (int ks = 0; ks < 16; ++ks) {
        const int k = kc * 512 + ks * 32 + kg * 8;
        bf16x8 a[4], bv[2];
#pragma unroll
        for (int i = 0; i < 4; ++i)
            a[i] = *reinterpret_cast<const bf16x8*>(gs + (size_t)(c0 + i * 16 + lrow) * NPOS + k);
#pragma unroll
        for (int j = 0; j < 2; ++j)
            bv[j] = *reinterpret_cast<const bf16x8*>(E + (size_t)(n0 + j * 16 + lrow) * NPOS + k);
#pragma unroll
        for (int i = 0; i < 4; ++i)
#pragma unroll
            for (int j = 0; j < 2; ++j)
                acc[i][j] = MFMA(a[i], bv[j], acc[i][j]);
    }
#pragma unroll
    for (int i = 0; i < 4; ++i)
#pragma unroll
        for (int j = 0; j < 2; ++j) {
            const int n = n0 + j * 16 + lrow;
            const int c = c0 + i * 16 + kg * 4;
            *reinterpret_cast<fvec4*>(partial + ((size_t)kc * NPOS + n) * IC + c) = acc[i][j];
        }
}

// ---------------- reduce partials -> yT[b][n][c] bf16 ----------------
__global__ __launch_bounds__(256) void k_reduce(
    const float* __restrict__ partial, unsigned short* __restrict__ yT, int b)
{
    const int idx = blockIdx.x * 256 + threadIdx.x;   // over NPOS*IC/4
    const fvec4* p = reinterpret_cast<const fvec4*>(partial);
    fvec4 s = p[idx];
#pragma unroll
    for (int kc = 1; kc < 8; ++kc) {
        fvec4 v = p[(size_t)kc * (NPOS * IC / 4) + idx];
        s[0] += v[0]; s[1] += v[1]; s[2] += v[2]; s[3] += v[3];
    }
    ushort4 o;
    o.x = f2bf(s[0]); o.y = f2bf(s[1]); o.z = f2bf(s[2]); o.w = f2bf(s[3]);
    *reinterpret_cast<ushort4*>(yT + (size_t)b * NPOS * IC + (size_t)idx * 4) = o;
}

// ---------------- final conv + residual: 64x64 per wave ----------------
__global__ __launch_bounds__(256) void k_conv(
    const float* __restrict__ x, const unsigned short* __restrict__ Wbf, const float* __restrict__ Wb,
    const unsigned short* __restrict__ yT, float* __restrict__ out)
{
    const int w    = threadIdx.x >> 6;
    const int lane = threadIdx.x & 63;
    const int lrow = lane & 15;
    const int kg   = lane >> 4;
    const int gwid = blockIdx.x * 4 + w;      // 0..2047
    const int ob   = gwid & 3;                // o-block of 64
    const int nb   = (gwid >> 2) & 63;        // n-block of 64
    const int b    = gwid >> 8;
    const int o0   = ob * 64;
    const int n0   = nb * 64;

    const unsigned short* Y = yT + (size_t)b * NPOS * IC;
    f32x4 acc[4][4] = {};
#pragma unroll
    for (int ks = 0; ks < 4; ++ks) {
        const int k = ks * 32 + kg * 8;
        bf16x8 a[4], bv[4];
#pragma unroll
        for (int i = 0; i < 4; ++i) {
            a[i]  = *reinterpret_cast<const bf16x8*>(Wbf + (size_t)(o0 + i * 16 + lrow) * IC + k);
            bv[i] = *reinterpret_cast<const bf16x8*>(Y + (size_t)(n0 + i * 16 + lrow) * IC + k);
        }
#pragma unroll
        for (int i = 0; i < 4; ++i)
#pragma unroll
            for (int j = 0; j < 4; ++j)
                acc[i][j] = MFMA(a[i], bv[j], acc[i][j]);
    }
#pragma unroll
    for (int i = 0; i < 4; ++i) {
        const int o = o0 + i * 16 + kg * 4;
#pragma unroll
        for (int j = 0; j < 4; ++j) {
            const int n = n0 + j * 16 + lrow;
#pragma unroll
            for (int r = 0; r < 4; ++r) {
                const size_t off = ((size_t)b * CIN + o + r) * NPOS + n;
                out[off] = acc[i][j][r] + x[off] + Wb[o + r];
            }
        }
    }
}

extern "C" void kernel_launch(void* const* d_in, const int* in_sizes, int n_in,
                              void* d_out, int out_size, void* d_ws, size_t ws_size,
                              hipStream_t stream)
{
    const float* x  = (const float*)d_in[0];
    const float* gw = (const float*)d_in[1];
    const float* gb = (const float*)d_in[2];
    const float* tw = (const float*)d_in[3];
    const float* tb = (const float*)d_in[4];
    const float* pw = (const float*)d_in[5];
    const float* pb = (const float*)d_in[6];
    const float* Ww = (const float*)d_in[7];
    const float* Wb = (const float*)d_in[8];
    float* out = (float*)d_out;

    char* ws = (char*)d_ws;
    size_t off = 0;
    auto alloc = [&](size_t bytes) -> char* {
        char* p = ws + off;
        off += (bytes + 255) & ~(size_t)255;
        return p;
    };
    const size_t xTB   = (size_t)NB * NPOS * CIN * 2;          // 16.8 MB each
    const size_t projB = (size_t)NB * NPOS * IC * 2;           // 8.4 MB each
    unsigned short* xT_h = (unsigned short*)alloc(xTB);        // xT_h+xT_l double as E later
    unsigned short* xT_l = (unsigned short*)alloc(xTB);
    unsigned short* w_h  = (unsigned short*)alloc((size_t)384 * 256 * 2);
    unsigned short* w_l  = (unsigned short*)alloc((size_t)384 * 256 * 2);
    unsigned short* Wbf  = (unsigned short*)alloc((size_t)CIN * IC * 2);
    unsigned short* th_hi = (unsigned short*)alloc(projB);
    unsigned short* th_lo = (unsigned short*)alloc(projB);
    unsigned short* ph_hi = (unsigned short*)alloc(projB);
    unsigned short* ph_lo = (unsigned short*)alloc(projB);
    unsigned short* gT    = (unsigned short*)alloc(projB);
    float* f       = (float*)alloc((size_t)NPOS * NPOS * 4);   // 67 MB (per-batch reuse)
    float* cmax    = (float*)alloc((size_t)NB * NPOS * 4);
    float* psum    = (float*)alloc((size_t)64 * NPOS * 4);
    unsigned short* gs = (unsigned short*)alloc((size_t)IC * NPOS * 2);
    float* partial = (float*)alloc((size_t)8 * NPOS * IC * 4); // 16.8 MB (per-batch reuse)
    unsigned short* yT = (unsigned short*)alloc(projB);        // 8.4 MB
    unsigned short* E  = xT_h;   // alias: 33.55 MB spans xT_h+xT_l, both dead after k_proj

    k_split_x<<<dim3(64, 4, 8), 256, 0, stream>>>(x, xT_h, xT_l);
    k_split_w<<<96, 256, 0, stream>>>(gw, tw, pw, w_h, w_l);
    k_cvt_w<<<32, 256, 0, stream>>>(Ww, Wbf);
    k_init_cmax<<<NB * NPOS / 256, 256, 0, stream>>>(cmax);
    k_proj<<<dim3(16, 6, 8), 256, 0, stream>>>(xT_h, xT_l, w_h, w_l, gb, tb, pb,
                                               th_hi, th_lo, ph_hi, ph_lo, gT);

    for (int b = 0; b < NB; ++b) {
        float* cm = cmax + (size_t)b * NPOS;
        k_gemm1<<<1024, 256, 0, stream>>>(th_hi, th_lo, ph_hi, ph_lo, f, cm, b);
        k_exp<<<dim3(16, 64), 256, 0, stream>>>(f, cm, E, psum);
        k_prep<<<dim3(16, 8), 256, 0, stream>>>(psum, gT + (size_t)b * IC * NPOS, gs);
        k_gemm2<<<512, 256, 0, stream>>>(E, gs, partial);
        k_reduce<<<512, 256, 0, stream>>>(partial, yT, b);
    }
    k_conv<<<dim3(512), 256, 0, stream>>>(x, Wbf, Wb, yT, out);
}

// Round 5
// 677.865 us; speedup vs baseline: 1.7107x; 1.2419x over previous
//
#include <hip/hip_runtime.h>
#include <hip/hip_bf16.h>

// NonLocalBlock2D: x[8,256,64,64] fp32
// All-fp16 pipeline (f logits kept fp32):
//   k_prep_w  : weights -> wAll fp16 [384][256] (g;theta;phi stacked), Wc fp16 [256][128]
//   k_split_x : transpose x -> xT fp16 [b][n][c]
//   k_proj    : fp16 GEMM 64x64/wave -> th/ph fp16 [b][n][c], gT fp16 [b][c][n]
//   k_gemm1   : f fp32 = theta·phi (fp16 MFMA); epilogue deterministic atomicMax -> cmax
//   k_exp     : E[n][m] = fp16(exp(f-cmax[m])), psum[64][m] partial column sums
//   k_prep    : gs[c][m] = fp16(g[c][m] / colsum[m])
//   k_gemm2   : fp16 GEMM partial[kc][n][c] = E·gs over m-chunks (kc=8)
//   k_reduce  : yT[b][n][c] fp16 = sum_kc partial
//   k_conv    : out = Wc·yT + Wb + x

#define IC   128
#define CIN  256
#define NPOS 4096
#define NB   8

typedef _Float16 f16;
typedef __attribute__((ext_vector_type(8))) _Float16 f16x8;
typedef __attribute__((ext_vector_type(4))) _Float16 f16x4;
typedef __attribute__((ext_vector_type(4))) float f32x4;
typedef __attribute__((ext_vector_type(4))) float fvec4;

#define MFMA16(a, b, c) __builtin_amdgcn_mfma_f32_16x16x32_f16((a), (b), (c), 0, 0, 0)

// Deterministic float atomic max (max is exact & order-independent).
static __device__ inline void atomicMaxFloat(float* addr, float val) {
    if (val >= 0.0f)
        atomicMax((int*)addr, __float_as_int(val));
    else
        atomicMin((unsigned int*)addr, (unsigned int)__float_as_int(val));
}

// ---------------- weight prep: wAll fp16 [384][256], Wc fp16 [256][128] ----------------
__global__ __launch_bounds__(256) void k_prep_w(
    const float* __restrict__ gw, const float* __restrict__ tw, const float* __restrict__ pw,
    const float* __restrict__ Ww, f16* __restrict__ wAll, f16* __restrict__ Wc)
{
    const int idx = (blockIdx.x * 256 + threadIdx.x) * 4;
    if (idx < 384 * 256) {
        const int row = idx >> 8, col = idx & 255;
        const float* src = (row < 128) ? (gw + row * 256)
                         : (row < 256) ? (tw + (row - 128) * 256)
                                       : (pw + (row - 256) * 256);
        fvec4 v = *reinterpret_cast<const fvec4*>(src + col);
        f16x4 o = { (f16)v[0], (f16)v[1], (f16)v[2], (f16)v[3] };
        *reinterpret_cast<f16x4*>(wAll + idx) = o;
    } else {
        const int j = idx - 384 * 256;          // over 256*128
        fvec4 v = *reinterpret_cast<const fvec4*>(Ww + j);
        f16x4 o = { (f16)v[0], (f16)v[1], (f16)v[2], (f16)v[3] };
        *reinterpret_cast<f16x4*>(Wc + j) = o;
    }
}

// ---------------- transpose x: [b][c][n] fp32 -> [b][n][c] fp16 ----------------
__global__ __launch_bounds__(256) void k_split_x(
    const float* __restrict__ x, f16* __restrict__ xT)
{
    __shared__ float tile[64][65];
    const int b  = blockIdx.z;
    const int c0 = blockIdx.y * 64;
    const int n0 = blockIdx.x * 64;
    const int t  = threadIdx.x;
    {
        const int cc = t >> 4, nn = (t & 15) * 4;
        const float* src = x + ((size_t)b * CIN + c0) * NPOS + n0;
#pragma unroll
        for (int p = 0; p < 4; ++p) {
            fvec4 v = *reinterpret_cast<const fvec4*>(src + (size_t)(cc + p * 16) * NPOS + nn);
            tile[cc + p * 16][nn + 0] = v[0];
            tile[cc + p * 16][nn + 1] = v[1];
            tile[cc + p * 16][nn + 2] = v[2];
            tile[cc + p * 16][nn + 3] = v[3];
        }
    }
    __syncthreads();
    {
        const int c4 = (t & 15) * 4, nr = t >> 4;
#pragma unroll
        for (int p = 0; p < 4; ++p) {
            const int n = nr + p * 16;
            f16x4 o = { (f16)tile[c4 + 0][n], (f16)tile[c4 + 1][n],
                        (f16)tile[c4 + 2][n], (f16)tile[c4 + 3][n] };
            *reinterpret_cast<f16x4*>(xT + ((size_t)b * NPOS + n0 + n) * CIN + c0 + c4) = o;
        }
    }
}

// ---------------- projections: fp16 GEMM, 64x64 per wave ----------------
__global__ __launch_bounds__(256) void k_proj(
    const f16* __restrict__ xT, const f16* __restrict__ wAll,
    const float* __restrict__ gb, const float* __restrict__ tb, const float* __restrict__ pb,
    f16* __restrict__ th, f16* __restrict__ ph, f16* __restrict__ gT)
{
    const int w    = threadIdx.x >> 6;
    const int lane = threadIdx.x & 63;
    const int lrow = lane & 15;
    const int kg   = lane >> 4;
    const int b    = blockIdx.z;
    const int c0   = blockIdx.y * 64;              // [0,384)
    const int n0   = blockIdx.x * 256 + w * 64;

    const f16* X = xT + (size_t)b * NPOS * CIN;

    f32x4 acc[4][4] = {};
#pragma unroll
    for (int ks = 0; ks < 8; ++ks) {
        const int k = ks * 32 + kg * 8;
        f16x8 a[4], bv[4];
#pragma unroll
        for (int i = 0; i < 4; ++i) {
            a[i]  = *reinterpret_cast<const f16x8*>(wAll + (size_t)(c0 + i * 16 + lrow) * CIN + k);
            bv[i] = *reinterpret_cast<const f16x8*>(X + (size_t)(n0 + i * 16 + lrow) * CIN + k);
        }
#pragma unroll
        for (int i = 0; i < 4; ++i)
#pragma unroll
            for (int j = 0; j < 4; ++j)
                acc[i][j] = MFMA16(a[i], bv[j], acc[i][j]);
    }
    const int set = c0 >> 7;                 // 0:g 1:theta 2:phi
    if (set == 0) {
#pragma unroll
        for (int i = 0; i < 4; ++i) {
            const int c = c0 + i * 16 + kg * 4;
#pragma unroll
            for (int j = 0; j < 4; ++j) {
                const int n = n0 + j * 16 + lrow;
#pragma unroll
                for (int r = 0; r < 4; ++r)
                    gT[((size_t)b * IC + c + r) * NPOS + n] = (f16)(acc[i][j][r] + gb[c + r]);
            }
        }
    } else {
        const float* Bi = (set == 1) ? tb : pb;
        f16* dst = (set == 1) ? th : ph;
        const int cl0 = (c0 & 127);
#pragma unroll
        for (int i = 0; i < 4; ++i) {
            const int c = cl0 + i * 16 + kg * 4;
#pragma unroll
            for (int j = 0; j < 4; ++j) {
                const int n = n0 + j * 16 + lrow;
                f16x4 o = { (f16)(acc[i][j][0] + Bi[c + 0]), (f16)(acc[i][j][1] + Bi[c + 1]),
                            (f16)(acc[i][j][2] + Bi[c + 2]), (f16)(acc[i][j][3] + Bi[c + 3]) };
                *reinterpret_cast<f16x4*>(dst + ((size_t)b * NPOS + n) * IC + c) = o;
            }
        }
    }
}

// ---------------- init cmax for all batches ----------------
__global__ __launch_bounds__(256) void k_init_cmax(float* __restrict__ cmax)
{
    cmax[blockIdx.x * 256 + threadIdx.x] = -3.0e38f;
}

// ---- GEMM1: f[n][m] = theta[n]·phi[m] fp32; epilogue column max -> cmax ----
__global__ __launch_bounds__(256) void k_gemm1(
    const f16* __restrict__ th, const f16* __restrict__ ph,
    float* __restrict__ f, float* __restrict__ cmax, int b)
{
    const int w    = threadIdx.x >> 6;
    const int lane = threadIdx.x & 63;
    const int lrow = lane & 15;
    const int kg   = lane >> 4;
    const int tid  = blockIdx.x * 4 + w;      // 0..4095
    const int n0   = (tid >> 6) * 64;
    const int m0   = (tid & 63) * 64;

    const f16* A = th + (size_t)b * NPOS * IC;
    const f16* B = ph + (size_t)b * NPOS * IC;

    f32x4 acc[4][4] = {};
#pragma unroll
    for (int ks = 0; ks < 4; ++ks) {
        const int k = ks * 32 + kg * 8;
        f16x8 a[4], bv[4];
#pragma unroll
        for (int i = 0; i < 4; ++i) {
            a[i]  = *reinterpret_cast<const f16x8*>(A + (size_t)(n0 + i * 16 + lrow) * IC + k);
            bv[i] = *reinterpret_cast<const f16x8*>(B + (size_t)(m0 + i * 16 + lrow) * IC + k);
        }
#pragma unroll
        for (int i = 0; i < 4; ++i)
#pragma unroll
            for (int j = 0; j < 4; ++j)
                acc[i][j] = MFMA16(a[i], bv[j], acc[i][j]);
    }
#pragma unroll
    for (int i = 0; i < 4; ++i)
#pragma unroll
        for (int j = 0; j < 4; ++j)
#pragma unroll
            for (int r = 0; r < 4; ++r)
                f[(size_t)(n0 + i * 16 + kg * 4 + r) * NPOS + m0 + j * 16 + lrow] = acc[i][j][r];

    // column max over this wave's 64 rows, for its 64 columns
#pragma unroll
    for (int j = 0; j < 4; ++j) {
        float cm = -3.0e38f;
#pragma unroll
        for (int i = 0; i < 4; ++i)
#pragma unroll
            for (int r = 0; r < 4; ++r)
                cm = fmaxf(cm, acc[i][j][r]);
        cm = fmaxf(cm, __shfl_xor(cm, 16));
        cm = fmaxf(cm, __shfl_xor(cm, 32));
        if (kg == 0)
            atomicMaxFloat(&cmax[m0 + j * 16 + lrow], cm);
    }
}

// ---------------- E = fp16(exp(f - cmax)), psum[64] partial column sums ----------------
__global__ __launch_bounds__(256) void k_exp(
    const float* __restrict__ f, const float* __restrict__ cmax,
    f16* __restrict__ E, float* __restrict__ psum)
{
    const int t    = threadIdx.x;
    const int c4   = (t & 63) * 4;
    const int rsub = t >> 6;
    const int col  = blockIdx.x * 256 + c4;
    fvec4 cm = *reinterpret_cast<const fvec4*>(cmax + col);
    fvec4 s = {0.f, 0.f, 0.f, 0.f};
    const int r0 = blockIdx.y * 64 + rsub;
#pragma unroll 4
    for (int it = 0; it < 16; ++it) {
        const int row = r0 + it * 4;
        fvec4 v = *reinterpret_cast<const fvec4*>(f + (size_t)row * NPOS + col);
        float e0 = __expf(v[0] - cm[0]);
        float e1 = __expf(v[1] - cm[1]);
        float e2 = __expf(v[2] - cm[2]);
        float e3 = __expf(v[3] - cm[3]);
        s[0] += e0; s[1] += e1; s[2] += e2; s[3] += e3;
        f16x4 o = { (f16)e0, (f16)e1, (f16)e2, (f16)e3 };
        *reinterpret_cast<f16x4*>(E + (size_t)row * NPOS + col) = o;
    }
    __shared__ fvec4 sm[256];
    sm[t] = s;
    __syncthreads();
    if (rsub == 0) {
        fvec4 a = sm[t], b = sm[t + 64], c = sm[t + 128], d = sm[t + 192];
        fvec4 o;
        o[0] = (a[0] + b[0]) + (c[0] + d[0]);
        o[1] = (a[1] + b[1]) + (c[1] + d[1]);
        o[2] = (a[2] + b[2]) + (c[2] + d[2]);
        o[3] = (a[3] + b[3]) + (c[3] + d[3]);
        *reinterpret_cast<fvec4*>(psum + (size_t)blockIdx.y * NPOS + col) = o;
    }
}

// ---------------- gs[c][m] = fp16(g[c][m] / colsum[m]) ----------------
__global__ __launch_bounds__(256) void k_prep(
    const float* __restrict__ psum, const f16* __restrict__ gTb, f16* __restrict__ gs)
{
    const int m = blockIdx.x * 256 + threadIdx.x;
    float s = 0.f;
#pragma unroll 8
    for (int i = 0; i < 64; ++i)
        s += psum[(size_t)i * NPOS + m];
    const float rc = 1.0f / s;
    const int cb = blockIdx.y * 16;
#pragma unroll
    for (int j = 0; j < 16; ++j) {
        const int c = cb + j;
        gs[(size_t)c * NPOS + m] = (f16)((float)gTb[(size_t)c * NPOS + m] * rc);
    }
}

// ---------------- GEMM2: partial[kc][n][c] = sum_{m chunk} gs[c][m]·E[n][m] ----------------
__global__ __launch_bounds__(256) void k_gemm2(
    const f16* __restrict__ E, const f16* __restrict__ gs, float* __restrict__ partial)
{
    const int w    = threadIdx.x >> 6;
    const int lane = threadIdx.x & 63;
    const int lrow = lane & 15;
    const int kg   = lane >> 4;
    const int gwid = blockIdx.x * 4 + w;      // 0..2047
    const int kc   = gwid & 7;                // m-chunk of 512
    const int nb   = (gwid >> 3) & 127;       // n-block of 32
    const int cb   = gwid >> 10;              // c-block of 64
    const int c0   = cb * 64;
    const int n0   = nb * 32;

    f32x4 acc[4][2] = {};
#pragma unroll 4
    for (int ks = 0; ks < 16; ++ks) {
        const int k = kc * 512 + ks * 32 + kg * 8;
        f16x8 a[4], bv[2];
#pragma unroll
        for (int i = 0; i < 4; ++i)
            a[i] = *reinterpret_cast<const f16x8*>(gs + (size_t)(c0 + i * 16 + lrow) * NPOS + k);
#pragma unroll
        for (int j = 0; j < 2; ++j)
            bv[j] = *reinterpret_cast<const f16x8*>(E + (size_t)(n0 + j * 16 + lrow) * NPOS + k);
#pragma unroll
        for (int i = 0; i < 4; ++i)
#pragma unroll
            for (int j = 0; j < 2; ++j)
                acc[i][j] = MFMA16(a[i], bv[j], acc[i][j]);
    }
#pragma unroll
    for (int i = 0; i < 4; ++i)
#pragma unroll
        for (int j = 0; j < 2; ++j) {
            const int n = n0 + j * 16 + lrow;
            const int c = c0 + i * 16 + kg * 4;
            *reinterpret_cast<fvec4*>(partial + ((size_t)kc * NPOS + n) * IC + c) = acc[i][j];
        }
}

// ---------------- reduce partials -> yT[b][n][c] fp16 ----------------
__global__ __launch_bounds__(256) void k_reduce(
    const float* __restrict__ partial, f16* __restrict__ yT, int b)
{
    const int idx = blockIdx.x * 256 + threadIdx.x;   // over NPOS*IC/4
    const fvec4* p = reinterpret_cast<const fvec4*>(partial);
    fvec4 s = p[idx];
#pragma unroll
    for (int kc = 1; kc < 8; ++kc) {
        fvec4 v = p[(size_t)kc * (NPOS * IC / 4) + idx];
        s[0] += v[0]; s[1] += v[1]; s[2] += v[2]; s[3] += v[3];
    }
    f16x4 o = { (f16)s[0], (f16)s[1], (f16)s[2], (f16)s[3] };
    *reinterpret_cast<f16x4*>(yT + (size_t)b * NPOS * IC + (size_t)idx * 4) = o;
}

// ---------------- final conv + residual: 64x64 per wave ----------------
__global__ __launch_bounds__(256) void k_conv(
    const float* __restrict__ x, const f16* __restrict__ Wc, const float* __restrict__ Wb,
    const f16* __restrict__ yT, float* __restrict__ out)
{
    const int w    = threadIdx.x >> 6;
    const int lane = threadIdx.x & 63;
    const int lrow = lane & 15;
    const int kg   = lane >> 4;
    const int gwid = blockIdx.x * 4 + w;      // 0..2047
    const int ob   = gwid & 3;                // o-block of 64
    const int nb   = (gwid >> 2) & 63;        // n-block of 64
    const int b    = gwid >> 8;
    const int o0   = ob * 64;
    const int n0   = nb * 64;

    const f16* Y = yT + (size_t)b * NPOS * IC;
    f32x4 acc[4][4] = {};
#pragma unroll
    for (int ks = 0; ks < 4; ++ks) {
        const int k = ks * 32 + kg * 8;
        f16x8 a[4], bv[4];
#pragma unroll
        for (int i = 0; i < 4; ++i) {
            a[i]  = *reinterpret_cast<const f16x8*>(Wc + (size_t)(o0 + i * 16 + lrow) * IC + k);
            bv[i] = *reinterpret_cast<const f16x8*>(Y + (size_t)(n0 + i * 16 + lrow) * IC + k);
        }
#pragma unroll
        for (int i = 0; i < 4; ++i)
#pragma unroll
            for (int j = 0; j < 4; ++j)
                acc[i][j] = MFMA16(a[i], bv[j], acc[i][j]);
    }
#pragma unroll
    for (int i = 0; i < 4; ++i) {
        const int o = o0 + i * 16 + kg * 4;
#pragma unroll
        for (int j = 0; j < 4; ++j) {
            const int n = n0 + j * 16 + lrow;
#pragma unroll
            for (int r = 0; r < 4; ++r) {
                const size_t off = ((size_t)b * CIN + o + r) * NPOS + n;
                out[off] = acc[i][j][r] + x[off] + Wb[o + r];
            }
        }
    }
}

extern "C" void kernel_launch(void* const* d_in, const int* in_sizes, int n_in,
                              void* d_out, int out_size, void* d_ws, size_t ws_size,
                              hipStream_t stream)
{
    const float* x  = (const float*)d_in[0];
    const float* gw = (const float*)d_in[1];
    const float* gb = (const float*)d_in[2];
    const float* tw = (const float*)d_in[3];
    const float* tb = (const float*)d_in[4];
    const float* pw = (const float*)d_in[5];
    const float* pb = (const float*)d_in[6];
    const float* Ww = (const float*)d_in[7];
    const float* Wb = (const float*)d_in[8];
    float* out = (float*)d_out;

    char* ws = (char*)d_ws;
    size_t off = 0;
    auto alloc = [&](size_t bytes) -> char* {
        char* p = ws + off;
        off += (bytes + 255) & ~(size_t)255;
        return p;
    };
    f16* xT   = (f16*)alloc((size_t)NB * NPOS * CIN * 2);      // 16.8 MB
    f16* wAll = (f16*)alloc((size_t)384 * 256 * 2);
    f16* Wc   = (f16*)alloc((size_t)CIN * IC * 2);
    f16* th   = (f16*)alloc((size_t)NB * NPOS * IC * 2);       // 8.4 MB
    f16* ph   = (f16*)alloc((size_t)NB * NPOS * IC * 2);
    f16* gT   = (f16*)alloc((size_t)NB * NPOS * IC * 2);
    float* f  = (float*)alloc((size_t)NPOS * NPOS * 4);        // 67 MB (per-batch reuse)
    float* cmax = (float*)alloc((size_t)NB * NPOS * 4);
    float* psum = (float*)alloc((size_t)64 * NPOS * 4);
    f16* gs   = (f16*)alloc((size_t)IC * NPOS * 2);
    float* partial = (float*)alloc((size_t)8 * NPOS * IC * 4); // 16.8 MB (per-batch reuse)
    f16* yT   = (f16*)alloc((size_t)NB * NPOS * IC * 2);
    f16* E    = (f16*)alloc((size_t)NPOS * NPOS * 2);          // 33.6 MB (per-batch reuse)

    k_prep_w<<<128, 256, 0, stream>>>(gw, tw, pw, Ww, wAll, Wc);
    k_split_x<<<dim3(64, 4, 8), 256, 0, stream>>>(x, xT);
    k_init_cmax<<<NB * NPOS / 256, 256, 0, stream>>>(cmax);
    k_proj<<<dim3(16, 6, 8), 256, 0, stream>>>(xT, wAll, gb, tb, pb, th, ph, gT);

    for (int b = 0; b < NB; ++b) {
        float* cm = cmax + (size_t)b * NPOS;
        k_gemm1<<<1024, 256, 0, stream>>>(th, ph, f, cm, b);
        k_exp<<<dim3(16, 64), 256, 0, stream>>>(f, cm, E, psum);
        k_prep<<<dim3(16, 8), 256, 0, stream>>>(psum, gT + (size_t)b * IC * NPOS, gs);
        k_gemm2<<<512, 256, 0, stream>>>(E, gs, partial);
        k_reduce<<<512, 256, 0, stream>>>(partial, yT, b);
    }
    k_conv<<<dim3(512), 256, 0, stream>>>(x, Wc, Wb, yT, out);
}

// Round 6
// 597.683 us; speedup vs baseline: 1.9402x; 1.1342x over previous
//
#include <hip/hip_runtime.h>
#include <hip/hip_bf16.h>

// NonLocalBlock2D: x[8,256,64,64] fp32
// All-fp16 pipeline (f logits fp32), batches processed in PAIRS:
//   k_prep_w  : weights -> wAll fp16 [384][256], Wc fp16 [256][128]
//   k_split_x : transpose x -> xT fp16 [b][n][c]
//   k_proj    : fp16 GEMM 64x64/wave -> th/ph fp16 [b][n][c], gT fp16 [b][c][n]
//   k_gemm1   : f fp32 = theta·phi; epilogue writes per-(64-row-block, col)
//               lmax/lsum (deterministic, no atomics). k_exp is GONE.
//   k_prep    : cmax[m], crcp[m] from lmax/lsum; gs[c][m] = fp16(g[c][m]*crcp[m])
//   k_gemm2   : P computed on the fly: exp(f-cmax) -> fp16 MFMA vs gs -> partial
//   k_reduce  : yT[b][n][c] fp16 = sum_kc partial
//   k_conv    : out = Wc·yT + Wb + x

#define IC   128
#define CIN  256
#define NPOS 4096
#define NB   8

typedef _Float16 f16;
typedef __attribute__((ext_vector_type(8))) _Float16 f16x8;
typedef __attribute__((ext_vector_type(4))) _Float16 f16x4;
typedef __attribute__((ext_vector_type(4))) float f32x4;
typedef __attribute__((ext_vector_type(4))) float fvec4;

#define MFMA16(a, b, c) __builtin_amdgcn_mfma_f32_16x16x32_f16((a), (b), (c), 0, 0, 0)

// ---------------- weight prep: wAll fp16 [384][256], Wc fp16 [256][128] ----------------
__global__ __launch_bounds__(256) void k_prep_w(
    const float* __restrict__ gw, const float* __restrict__ tw, const float* __restrict__ pw,
    const float* __restrict__ Ww, f16* __restrict__ wAll, f16* __restrict__ Wc)
{
    const int idx = (blockIdx.x * 256 + threadIdx.x) * 4;
    if (idx < 384 * 256) {
        const int row = idx >> 8, col = idx & 255;
        const float* src = (row < 128) ? (gw + row * 256)
                         : (row < 256) ? (tw + (row - 128) * 256)
                                       : (pw + (row - 256) * 256);
        fvec4 v = *reinterpret_cast<const fvec4*>(src + col);
        f16x4 o = { (f16)v[0], (f16)v[1], (f16)v[2], (f16)v[3] };
        *reinterpret_cast<f16x4*>(wAll + idx) = o;
    } else {
        const int j = idx - 384 * 256;          // over 256*128
        fvec4 v = *reinterpret_cast<const fvec4*>(Ww + j);
        f16x4 o = { (f16)v[0], (f16)v[1], (f16)v[2], (f16)v[3] };
        *reinterpret_cast<f16x4*>(Wc + j) = o;
    }
}

// ---------------- transpose x: [b][c][n] fp32 -> [b][n][c] fp16 ----------------
__global__ __launch_bounds__(256) void k_split_x(
    const float* __restrict__ x, f16* __restrict__ xT)
{
    __shared__ float tile[64][65];
    const int b  = blockIdx.z;
    const int c0 = blockIdx.y * 64;
    const int n0 = blockIdx.x * 64;
    const int t  = threadIdx.x;
    {
        const int cc = t >> 4, nn = (t & 15) * 4;
        const float* src = x + ((size_t)b * CIN + c0) * NPOS + n0;
#pragma unroll
        for (int p = 0; p < 4; ++p) {
            fvec4 v = *reinterpret_cast<const fvec4*>(src + (size_t)(cc + p * 16) * NPOS + nn);
            tile[cc + p * 16][nn + 0] = v[0];
            tile[cc + p * 16][nn + 1] = v[1];
            tile[cc + p * 16][nn + 2] = v[2];
            tile[cc + p * 16][nn + 3] = v[3];
        }
    }
    __syncthreads();
    {
        const int c4 = (t & 15) * 4, nr = t >> 4;
#pragma unroll
        for (int p = 0; p < 4; ++p) {
            const int n = nr + p * 16;
            f16x4 o = { (f16)tile[c4 + 0][n], (f16)tile[c4 + 1][n],
                        (f16)tile[c4 + 2][n], (f16)tile[c4 + 3][n] };
            *reinterpret_cast<f16x4*>(xT + ((size_t)b * NPOS + n0 + n) * CIN + c0 + c4) = o;
        }
    }
}

// ---------------- projections: fp16 GEMM, 64x64 per wave ----------------
__global__ __launch_bounds__(256) void k_proj(
    const f16* __restrict__ xT, const f16* __restrict__ wAll,
    const float* __restrict__ gb, const float* __restrict__ tb, const float* __restrict__ pb,
    f16* __restrict__ th, f16* __restrict__ ph, f16* __restrict__ gT)
{
    const int w    = threadIdx.x >> 6;
    const int lane = threadIdx.x & 63;
    const int lrow = lane & 15;
    const int kg   = lane >> 4;
    const int b    = blockIdx.z;
    const int c0   = blockIdx.y * 64;              // [0,384)
    const int n0   = blockIdx.x * 256 + w * 64;

    const f16* X = xT + (size_t)b * NPOS * CIN;

    f32x4 acc[4][4] = {};
#pragma unroll
    for (int ks = 0; ks < 8; ++ks) {
        const int k = ks * 32 + kg * 8;
        f16x8 a[4], bv[4];
#pragma unroll
        for (int i = 0; i < 4; ++i) {
            a[i]  = *reinterpret_cast<const f16x8*>(wAll + (size_t)(c0 + i * 16 + lrow) * CIN + k);
            bv[i] = *reinterpret_cast<const f16x8*>(X + (size_t)(n0 + i * 16 + lrow) * CIN + k);
        }
#pragma unroll
        for (int i = 0; i < 4; ++i)
#pragma unroll
            for (int j = 0; j < 4; ++j)
                acc[i][j] = MFMA16(a[i], bv[j], acc[i][j]);
    }
    const int set = c0 >> 7;                 // 0:g 1:theta 2:phi
    if (set == 0) {
#pragma unroll
        for (int i = 0; i < 4; ++i) {
            const int c = c0 + i * 16 + kg * 4;
#pragma unroll
            for (int j = 0; j < 4; ++j) {
                const int n = n0 + j * 16 + lrow;
#pragma unroll
                for (int r = 0; r < 4; ++r)
                    gT[((size_t)b * IC + c + r) * NPOS + n] = (f16)(acc[i][j][r] + gb[c + r]);
            }
        }
    } else {
        const float* Bi = (set == 1) ? tb : pb;
        f16* dst = (set == 1) ? th : ph;
        const int cl0 = (c0 & 127);
#pragma unroll
        for (int i = 0; i < 4; ++i) {
            const int c = cl0 + i * 16 + kg * 4;
#pragma unroll
            for (int j = 0; j < 4; ++j) {
                const int n = n0 + j * 16 + lrow;
                f16x4 o = { (f16)(acc[i][j][0] + Bi[c + 0]), (f16)(acc[i][j][1] + Bi[c + 1]),
                            (f16)(acc[i][j][2] + Bi[c + 2]), (f16)(acc[i][j][3] + Bi[c + 3]) };
                *reinterpret_cast<f16x4*>(dst + ((size_t)b * NPOS + n) * IC + c) = o;
            }
        }
    }
}

// ---- GEMM1 (pair): f[bi][n][m] = theta[n]·phi[m] fp32; epilogue lmax/lsum ----
__global__ __launch_bounds__(256) void k_gemm1(
    const f16* __restrict__ th, const f16* __restrict__ ph,
    float* __restrict__ f, float* __restrict__ lmax, float* __restrict__ lsum, int b0)
{
    const int w    = threadIdx.x >> 6;
    const int lane = threadIdx.x & 63;
    const int lrow = lane & 15;
    const int kg   = lane >> 4;
    const int gwid = blockIdx.x * 4 + w;      // 0..8191
    const int bi   = gwid >> 12;
    const int tid  = gwid & 4095;
    const int n0   = (tid >> 6) * 64;
    const int m0   = (tid & 63) * 64;

    const f16* A = th + (size_t)(b0 + bi) * NPOS * IC;
    const f16* B = ph + (size_t)(b0 + bi) * NPOS * IC;
    float* fb = f + (size_t)bi * NPOS * NPOS;

    f32x4 acc[4][4] = {};
#pragma unroll
    for (int ks = 0; ks < 4; ++ks) {
        const int k = ks * 32 + kg * 8;
        f16x8 a[4], bv[4];
#pragma unroll
        for (int i = 0; i < 4; ++i) {
            a[i]  = *reinterpret_cast<const f16x8*>(A + (size_t)(n0 + i * 16 + lrow) * IC + k);
            bv[i] = *reinterpret_cast<const f16x8*>(B + (size_t)(m0 + i * 16 + lrow) * IC + k);
        }
#pragma unroll
        for (int i = 0; i < 4; ++i)
#pragma unroll
            for (int j = 0; j < 4; ++j)
                acc[i][j] = MFMA16(a[i], bv[j], acc[i][j]);
    }
#pragma unroll
    for (int i = 0; i < 4; ++i)
#pragma unroll
        for (int j = 0; j < 4; ++j)
#pragma unroll
            for (int r = 0; r < 4; ++r)
                fb[(size_t)(n0 + i * 16 + kg * 4 + r) * NPOS + m0 + j * 16 + lrow] = acc[i][j][r];

    // per-column (64 rows of this wave) max and exp-sum; deterministic, no atomics
    const int rowblk = n0 >> 6;
#pragma unroll
    for (int j = 0; j < 4; ++j) {
        float cm = -3.0e38f;
#pragma unroll
        for (int i = 0; i < 4; ++i)
#pragma unroll
            for (int r = 0; r < 4; ++r)
                cm = fmaxf(cm, acc[i][j][r]);
        cm = fmaxf(cm, __shfl_xor(cm, 16));
        cm = fmaxf(cm, __shfl_xor(cm, 32));
        float s = 0.f;
#pragma unroll
        for (int i = 0; i < 4; ++i)
#pragma unroll
            for (int r = 0; r < 4; ++r)
                s += __expf(acc[i][j][r] - cm);
        s += __shfl_xor(s, 16);
        s += __shfl_xor(s, 32);
        if (kg == 0) {
            const size_t off = ((size_t)bi * 64 + rowblk) * NPOS + m0 + j * 16 + lrow;
            lmax[off] = cm;
            lsum[off] = s;
        }
    }
}

// ---- prep (pair): cmax/crcp from lmax/lsum; gs[c][m] = fp16(g[c][m]*crcp[m]) ----
__global__ __launch_bounds__(256) void k_prep(
    const float* __restrict__ lmax, const float* __restrict__ lsum,
    const f16* __restrict__ gT, float* __restrict__ cmaxp, f16* __restrict__ gs, int b0)
{
    const int bi = blockIdx.z;
    const int m  = blockIdx.x * 256 + threadIdx.x;
    const float* lm = lmax + (size_t)bi * 64 * NPOS;
    const float* ls = lsum + (size_t)bi * 64 * NPOS;
    float cm = -3.0e38f;
#pragma unroll 8
    for (int rb = 0; rb < 64; ++rb)
        cm = fmaxf(cm, lm[(size_t)rb * NPOS + m]);
    float s = 0.f;
#pragma unroll 8
    for (int rb = 0; rb < 64; ++rb)
        s += __expf(lm[(size_t)rb * NPOS + m] - cm) * ls[(size_t)rb * NPOS + m];
    const float rc = 1.0f / s;
    if (blockIdx.y == 0)
        cmaxp[(size_t)bi * NPOS + m] = cm;
    const f16* gb = gT + (size_t)(b0 + bi) * IC * NPOS;
    f16* gsb = gs + (size_t)bi * IC * NPOS;
    const int cb = blockIdx.y * 16;
#pragma unroll
    for (int j = 0; j < 16; ++j) {
        const int c = cb + j;
        gsb[(size_t)c * NPOS + m] = (f16)((float)gb[(size_t)c * NPOS + m] * rc);
    }
}

// ---- GEMM2 (pair): partial[bi][kc][n][c] = sum_{m chunk} gs[c][m]·exp(f[n][m]-cmax[m]) ----
__global__ __launch_bounds__(256) void k_gemm2(
    const float* __restrict__ f, const float* __restrict__ cmaxp,
    const f16* __restrict__ gs, float* __restrict__ partial)
{
    const int w    = threadIdx.x >> 6;
    const int lane = threadIdx.x & 63;
    const int lrow = lane & 15;
    const int kg   = lane >> 4;
    const int gwid = blockIdx.x * 4 + w;      // 0..4095
    const int bi   = gwid >> 11;
    const int rest = gwid & 2047;
    const int kc   = rest & 7;                // m-chunk of 512
    const int nb   = (rest >> 3) & 127;       // n-block of 32
    const int cb   = rest >> 10;              // c-block of 64
    const int c0   = cb * 64;
    const int n0   = nb * 32;

    const float* fb  = f + (size_t)bi * NPOS * NPOS;
    const float* cmb = cmaxp + (size_t)bi * NPOS;
    const f16* gsb   = gs + (size_t)bi * IC * NPOS;

    f32x4 acc[4][2] = {};
#pragma unroll 2
    for (int ks = 0; ks < 16; ++ks) {
        const int k = kc * 512 + ks * 32 + kg * 8;
        fvec4 cm0 = *reinterpret_cast<const fvec4*>(cmb + k);
        fvec4 cm1 = *reinterpret_cast<const fvec4*>(cmb + k + 4);
        f16x8 a[4], bv[2];
#pragma unroll
        for (int i = 0; i < 4; ++i)
            a[i] = *reinterpret_cast<const f16x8*>(gsb + (size_t)(c0 + i * 16 + lrow) * NPOS + k);
#pragma unroll
        for (int j = 0; j < 2; ++j) {
            const float* frow = fb + (size_t)(n0 + j * 16 + lrow) * NPOS + k;
            fvec4 fv0 = *reinterpret_cast<const fvec4*>(frow);
            fvec4 fv1 = *reinterpret_cast<const fvec4*>(frow + 4);
            f16x8 e;
            e[0] = (f16)__expf(fv0[0] - cm0[0]);
            e[1] = (f16)__expf(fv0[1] - cm0[1]);
            e[2] = (f16)__expf(fv0[2] - cm0[2]);
            e[3] = (f16)__expf(fv0[3] - cm0[3]);
            e[4] = (f16)__expf(fv1[0] - cm1[0]);
            e[5] = (f16)__expf(fv1[1] - cm1[1]);
            e[6] = (f16)__expf(fv1[2] - cm1[2]);
            e[7] = (f16)__expf(fv1[3] - cm1[3]);
            bv[j] = e;
        }
#pragma unroll
        for (int i = 0; i < 4; ++i)
#pragma unroll
            for (int j = 0; j < 2; ++j)
                acc[i][j] = MFMA16(a[i], bv[j], acc[i][j]);
    }
    float* pb = partial + ((size_t)bi * 8 + kc) * NPOS * IC;
#pragma unroll
    for (int i = 0; i < 4; ++i)
#pragma unroll
        for (int j = 0; j < 2; ++j) {
            const int n = n0 + j * 16 + lrow;
            const int c = c0 + i * 16 + kg * 4;
            *reinterpret_cast<fvec4*>(pb + (size_t)n * IC + c) = acc[i][j];
        }
}

// ---------------- reduce partials (pair) -> yT[b][n][c] fp16 ----------------
__global__ __launch_bounds__(256) void k_reduce(
    const float* __restrict__ partial, f16* __restrict__ yT, int b0)
{
    const int bi  = blockIdx.y;
    const int idx = blockIdx.x * 256 + threadIdx.x;   // over NPOS*IC/4
    const fvec4* p = reinterpret_cast<const fvec4*>(partial + (size_t)bi * 8 * NPOS * IC);
    fvec4 s = p[idx];
#pragma unroll
    for (int kc = 1; kc < 8; ++kc) {
        fvec4 v = p[(size_t)kc * (NPOS * IC / 4) + idx];
        s[0] += v[0]; s[1] += v[1]; s[2] += v[2]; s[3] += v[3];
    }
    f16x4 o = { (f16)s[0], (f16)s[1], (f16)s[2], (f16)s[3] };
    *reinterpret_cast<f16x4*>(yT + (size_t)(b0 + bi) * NPOS * IC + (size_t)idx * 4) = o;
}

// ---------------- final conv + residual: 64x64 per wave ----------------
__global__ __launch_bounds__(256) void k_conv(
    const float* __restrict__ x, const f16* __restrict__ Wc, const float* __restrict__ Wb,
    const f16* __restrict__ yT, float* __restrict__ out)
{
    const int w    = threadIdx.x >> 6;
    const int lane = threadIdx.x & 63;
    const int lrow = lane & 15;
    const int kg   = lane >> 4;
    const int gwid = blockIdx.x * 4 + w;      // 0..2047
    const int ob   = gwid & 3;                // o-block of 64
    const int nb   = (gwid >> 2) & 63;        // n-block of 64
    const int b    = gwid >> 8;
    const int o0   = ob * 64;
    const int n0   = nb * 64;

    const f16* Y = yT + (size_t)b * NPOS * IC;
    f32x4 acc[4][4] = {};
#pragma unroll
    for (int ks = 0; ks < 4; ++ks) {
        const int k = ks * 32 + kg * 8;
        f16x8 a[4], bv[4];
#pragma unroll
        for (int i = 0; i < 4; ++i) {
            a[i]  = *reinterpret_cast<const f16x8*>(Wc + (size_t)(o0 + i * 16 + lrow) * IC + k);
            bv[i] = *reinterpret_cast<const f16x8*>(Y + (size_t)(n0 + i * 16 + lrow) * IC + k);
        }
#pragma unroll
        for (int i = 0; i < 4; ++i)
#pragma unroll
            for (int j = 0; j < 4; ++j)
                acc[i][j] = MFMA16(a[i], bv[j], acc[i][j]);
    }
#pragma unroll
    for (int i = 0; i < 4; ++i) {
        const int o = o0 + i * 16 + kg * 4;
#pragma unroll
        for (int j = 0; j < 4; ++j) {
            const int n = n0 + j * 16 + lrow;
#pragma unroll
            for (int r = 0; r < 4; ++r) {
                const size_t off = ((size_t)b * CIN + o + r) * NPOS + n;
                out[off] = acc[i][j][r] + x[off] + Wb[o + r];
            }
        }
    }
}

extern "C" void kernel_launch(void* const* d_in, const int* in_sizes, int n_in,
                              void* d_out, int out_size, void* d_ws, size_t ws_size,
                              hipStream_t stream)
{
    const float* x  = (const float*)d_in[0];
    const float* gw = (const float*)d_in[1];
    const float* gb = (const float*)d_in[2];
    const float* tw = (const float*)d_in[3];
    const float* tb = (const float*)d_in[4];
    const float* pw = (const float*)d_in[5];
    const float* pb = (const float*)d_in[6];
    const float* Ww = (const float*)d_in[7];
    const float* Wb = (const float*)d_in[8];
    float* out = (float*)d_out;

    char* ws = (char*)d_ws;
    size_t off = 0;
    auto alloc = [&](size_t bytes) -> char* {
        char* p = ws + off;
        off += (bytes + 255) & ~(size_t)255;
        return p;
    };
    f16* xT   = (f16*)alloc((size_t)NB * NPOS * CIN * 2);        // 16.8 MB
    f16* wAll = (f16*)alloc((size_t)384 * 256 * 2);
    f16* Wc   = (f16*)alloc((size_t)CIN * IC * 2);
    f16* th   = (f16*)alloc((size_t)NB * NPOS * IC * 2);         // 8.4 MB
    f16* ph   = (f16*)alloc((size_t)NB * NPOS * IC * 2);
    f16* gT   = (f16*)alloc((size_t)NB * NPOS * IC * 2);
    float* f  = (float*)alloc((size_t)2 * NPOS * NPOS * 4);      // 134 MB (pair)
    float* lmax = (float*)alloc((size_t)2 * 64 * NPOS * 4);      // 2.1 MB
    float* lsum = (float*)alloc((size_t)2 * 64 * NPOS * 4);
    float* cmaxp = (float*)alloc((size_t)2 * NPOS * 4);
    f16* gs   = (f16*)alloc((size_t)2 * IC * NPOS * 2);          // 2.1 MB
    float* partial = (float*)alloc((size_t)2 * 8 * NPOS * IC * 4); // 33.6 MB (pair)
    f16* yT   = (f16*)alloc((size_t)NB * NPOS * IC * 2);         // 8.4 MB

    k_prep_w<<<128, 256, 0, stream>>>(gw, tw, pw, Ww, wAll, Wc);
    k_split_x<<<dim3(64, 4, 8), 256, 0, stream>>>(x, xT);
    k_proj<<<dim3(16, 6, 8), 256, 0, stream>>>(xT, wAll, gb, tb, pb, th, ph, gT);

    for (int b0 = 0; b0 < NB; b0 += 2) {
        k_gemm1<<<2048, 256, 0, stream>>>(th, ph, f, lmax, lsum, b0);
        k_prep<<<dim3(16, 8, 2), 256, 0, stream>>>(lmax, lsum, gT, cmaxp, gs, b0);
        k_gemm2<<<1024, 256, 0, stream>>>(f, cmaxp, gs, partial);
        k_reduce<<<dim3(512, 2), 256, 0, stream>>>(partial, yT, b0);
    }
    k_conv<<<dim3(512), 256, 0, stream>>>(x, Wc, Wb, yT, out);
}